// Round 16
// baseline (255.605 us; speedup 1.0000x reference)
//
#include <hip/hip_runtime.h>

namespace {

constexpr int kN  = 20000;
constexpr int kE  = 80000;
constexpr int kIn = 64;
constexpr int kH  = 32;
constexpr int kEA = 32;
constexpr int kT  = 64;
constexpr int kL  = 3;
constexpr float kEps = 1e-5f;

typedef __attribute__((ext_vector_type(8))) short bf16x8;
typedef __attribute__((ext_vector_type(4))) float f32x4;

__device__ inline unsigned short f2bf(float f) {
  unsigned u = __builtin_bit_cast(unsigned, f);
  unsigned r = (u + 0x7fff + ((u >> 16) & 1)) >> 16;  // RNE
  return (unsigned short)r;
}
__device__ inline float bf2f(unsigned short s) {
  unsigned u = ((unsigned)s) << 16;
  return __builtin_bit_cast(float, u);
}

// ---- hist + per-edge rank within destination (rank trick: old count) ----
__global__ __launch_bounds__(256) void hist_dst(const int* __restrict__ ei,
                                                int* __restrict__ cnt,
                                                int* __restrict__ rank) {
  const int e = blockIdx.x * 256 + threadIdx.x;
  if (e < kE) rank[e] = atomicAdd(&cnt[ei[kE + e]], 1);
}

// 1 block, 1024 threads; 20 elems/thread serial + wave shfl-scan + wave combine
__global__ __launch_bounds__(1024) void scan_nodes(const int* __restrict__ cnt,
                                                   int* __restrict__ off) {
  __shared__ int wsum[16];
  __shared__ int woff[16];
  const int tid = threadIdx.x, lane = tid & 63, wid = tid >> 6;
  constexpr int CH = 20;  // 1024*20 = 20480 >= kN
  const int base = tid * CH;
  int v[CH];
  int s = 0;
#pragma unroll
  for (int j = 0; j < CH; ++j) {
    const int i = base + j;
    const int c = (i < kN) ? cnt[i] : 0;
    v[j] = s;
    s += c;
  }
  int x = s;
#pragma unroll
  for (int d = 1; d < 64; d <<= 1) {
    int y = __shfl_up(x, d);
    if (lane >= d) x += y;
  }
  if (lane == 63) wsum[wid] = x;
  __syncthreads();
  if (tid < 16) {
    int t = wsum[tid];
    int xx = t;
#pragma unroll
    for (int d = 1; d < 16; d <<= 1) {
      int y = __shfl_up(xx, d);
      if (tid >= d) xx += y;
    }
    woff[tid] = xx - t;
  }
  __syncthreads();
  const int thrbase = woff[wid] + (x - s);
#pragma unroll
  for (int j = 0; j < CH; ++j) {
    const int i = base + j;
    if (i < kN) off[i] = thrbase + v[j];
  }
}

// ---- pack Wm[l] f32[32][1024] -> B-fragment-ordered bf16: frag[l][ct][lane][8]
__global__ __launch_bounds__(256) void pack_w(const float* __restrict__ emW,
                                              unsigned short* __restrict__ wbf) {
  const int idx = blockIdx.x * 256 + threadIdx.x;
  if (idx >= kL * 64 * 64) return;
  const int lane = idx & 63, ct = (idx >> 6) & 63, l = idx >> 12;
  const int k0 = (lane >> 4) * 8, c = ct * 16 + (lane & 15);
  const float* W = emW + (size_t)l * kEA * kH * kH;
  unsigned out[4];
#pragma unroll
  for (int p = 0; p < 4; ++p) {
    unsigned lo = f2bf(W[(size_t)(k0 + 2 * p) * (kH * kH) + c]);
    unsigned hi = f2bf(W[(size_t)(k0 + 2 * p + 1) * (kH * kH) + c]);
    out[p] = lo | (hi << 16);
  }
  *reinterpret_cast<uint4*>(wbf + (size_t)idx * 8) =
      make_uint4(out[0], out[1], out[2], out[3]);
}

// ---------------- h = x @ initW + initb (64-thr blocks) ----------------
__global__ __launch_bounds__(64) void init_proj(
    const float* __restrict__ x, const float* __restrict__ W,
    const float* __restrict__ b, float* __restrict__ h) {
  __shared__ float Wl[kIn * kH];
  __shared__ float bl[kH];
  const int tid = threadIdx.x;
  {
    const float4* Ws = reinterpret_cast<const float4*>(W);
    float4* Wd = reinterpret_cast<float4*>(Wl);
    for (int j = tid; j < kIn * kH / 4; j += 64) Wd[j] = Ws[j];
  }
  if (tid < kH) bl[tid] = b[tid];
  __syncthreads();
  const int node = blockIdx.x * 64 + tid;
  if (node >= kN) return;
  float xr[kIn];
  const float4* xp = reinterpret_cast<const float4*>(x + (size_t)node * kIn);
#pragma unroll
  for (int k4 = 0; k4 < kIn / 4; ++k4) {
    float4 v = xp[k4];
    xr[k4 * 4 + 0] = v.x; xr[k4 * 4 + 1] = v.y;
    xr[k4 * 4 + 2] = v.z; xr[k4 * 4 + 3] = v.w;
  }
  float* hp = h + (size_t)node * kH;
#pragma unroll
  for (int o = 0; o < kH; ++o) {
    float acc = bl[o];
#pragma unroll
    for (int k = 0; k < kIn; ++k) acc = fmaf(xr[k], Wl[k * kH + o], acc);
    hp[o] = acc;
  }
}

// ------- wave-independent MFMA edge MLP: 1 wave = 16 edges, all i -------
constexpr int HP  = 40;  // h LDS row pitch in ushorts (80 B)
constexpr int MPW = 36;  // msg LDS row pitch in f32 (144 B)
__global__ __launch_bounds__(256) void edge_msg_mfma(
    const float* __restrict__ attr, const int* __restrict__ ei,
    const int* __restrict__ off, const int* __restrict__ rank,
    const float* __restrict__ h, const unsigned short* __restrict__ wbf,
    const float* __restrict__ bm, float* __restrict__ msg_buf) {
  __shared__ float bml[kH * kH];               // 4 KB, block-shared
  __shared__ unsigned short hbuf[4][16 * HP];  // 4 x 1.25 KB, wave-private
  __shared__ float mbuf[4][16 * MPW];          // 4 x 2.25 KB, wave-private
  const int tid = threadIdx.x;
  const int wv = tid >> 6, lane = tid & 63;
  const int lr = lane & 15, lg = lane >> 4;
  const int base = (blockIdx.x * 4 + wv) * 16;  // this wave's 16 edges

  for (int j = tid; j < kH * kH; j += 256) bml[j] = bm[j];

  bf16x8 Af;
  {
    const float4* ap = reinterpret_cast<const float4*>(
        attr + (size_t)(base + lr) * kEA + lg * 8);
    float4 a0 = ap[0], a1 = ap[1];
    Af[0] = (short)f2bf(a0.x); Af[1] = (short)f2bf(a0.y);
    Af[2] = (short)f2bf(a0.z); Af[3] = (short)f2bf(a0.w);
    Af[4] = (short)f2bf(a1.x); Af[5] = (short)f2bf(a1.y);
    Af[6] = (short)f2bf(a1.z); Af[7] = (short)f2bf(a1.w);
  }

  {
    const int er = lane >> 2, q = lane & 3;
    const int src = ei[base + er];
    const float4* hp4 =
        reinterpret_cast<const float4*>(h + (size_t)src * kH + q * 8);
    float4 h0 = hp4[0], h1 = hp4[1];
    uint2 p0 = make_uint2(f2bf(h0.x) | ((unsigned)f2bf(h0.y) << 16),
                          f2bf(h0.z) | ((unsigned)f2bf(h0.w) << 16));
    uint2 p1 = make_uint2(f2bf(h1.x) | ((unsigned)f2bf(h1.y) << 16),
                          f2bf(h1.z) | ((unsigned)f2bf(h1.w) << 16));
    *reinterpret_cast<uint2*>(&hbuf[wv][0] + er * HP + q * 8) = p0;
    *reinterpret_cast<uint2*>(&hbuf[wv][0] + er * HP + q * 8 + 4) = p1;
  }

  __syncthreads();  // bml ready (hbuf is wave-private; barrier covers it too)

  float ma[4][2] = {{0.f, 0.f}, {0.f, 0.f}, {0.f, 0.f}, {0.f, 0.f}};
  const unsigned short* hrow = &hbuf[wv][0];

#pragma unroll
  for (int g = 0; g < 4; ++g) {  // il groups of 8
    bf16x8 hv0 = *reinterpret_cast<const bf16x8*>(hrow + (lg * 4 + 0) * HP + g * 8);
    bf16x8 hv1 = *reinterpret_cast<const bf16x8*>(hrow + (lg * 4 + 1) * HP + g * 8);
    bf16x8 hv2 = *reinterpret_cast<const bf16x8*>(hrow + (lg * 4 + 2) * HP + g * 8);
    bf16x8 hv3 = *reinterpret_cast<const bf16x8*>(hrow + (lg * 4 + 3) * HP + g * 8);
#pragma unroll
    for (int i8 = 0; i8 < 8; ++i8) {
      const int il = g * 8 + i8;
      bf16x8 B0 = *reinterpret_cast<const bf16x8*>(
          wbf + ((size_t)(il * 2 + 0) * 64 + lane) * 8);
      bf16x8 B1 = *reinterpret_cast<const bf16x8*>(
          wbf + ((size_t)(il * 2 + 1) * 64 + lane) * 8);
      const float b0 = bml[il * kH + lr];
      const float b1 = bml[il * kH + 16 + lr];
      f32x4 c0, c1;
      c0[0] = b0; c0[1] = b0; c0[2] = b0; c0[3] = b0;
      c1[0] = b1; c1[1] = b1; c1[2] = b1; c1[3] = b1;
      c0 = __builtin_amdgcn_mfma_f32_16x16x32_bf16(Af, B0, c0, 0, 0, 0);
      c1 = __builtin_amdgcn_mfma_f32_16x16x32_bf16(Af, B1, c1, 0, 0, 0);
      const float h0 = bf2f((unsigned short)hv0[i8]);
      const float h1 = bf2f((unsigned short)hv1[i8]);
      const float h2 = bf2f((unsigned short)hv2[i8]);
      const float h3 = bf2f((unsigned short)hv3[i8]);
      ma[0][0] = fmaf(fmaxf(c0[0], 0.f), h0, ma[0][0]);
      ma[1][0] = fmaf(fmaxf(c0[1], 0.f), h1, ma[1][0]);
      ma[2][0] = fmaf(fmaxf(c0[2], 0.f), h2, ma[2][0]);
      ma[3][0] = fmaf(fmaxf(c0[3], 0.f), h3, ma[3][0]);
      ma[0][1] = fmaf(fmaxf(c1[0], 0.f), h0, ma[0][1]);
      ma[1][1] = fmaf(fmaxf(c1[1], 0.f), h1, ma[1][1]);
      ma[2][1] = fmaf(fmaxf(c1[2], 0.f), h2, ma[2][1]);
      ma[3][1] = fmaf(fmaxf(c1[3], 0.f), h3, ma[3][1]);
    }
  }

  float* mrow = &mbuf[wv][0];
#pragma unroll
  for (int r = 0; r < 4; ++r) {
    mrow[(lg * 4 + r) * MPW + lr] = ma[r][0];
    mrow[(lg * 4 + r) * MPW + 16 + lr] = ma[r][1];
  }
  {
    const int er = lane >> 2, q = lane & 3;
    const int e = base + er;
    const int mp = off[ei[kE + e]] + rank[e];
    float4 v0 = *reinterpret_cast<const float4*>(mrow + er * MPW + q * 8);
    float4 v1 = *reinterpret_cast<const float4*>(mrow + er * MPW + q * 8 + 4);
    float* orow = msg_buf + (size_t)mp * kH + q * 8;
    *reinterpret_cast<float4*>(orow) = v0;
    *reinterpret_cast<float4*>(orow + 4) = v1;
  }
}

// ==== FUSED layer node phase: segsum+root+stats | spin-sync | norm+trans ====
// grid 79 x 256; all blocks co-resident (46 KB LDS -> 3 blocks/CU, need 27 CUs)
__global__ __launch_bounds__(256) void layer_fused(
    const float* __restrict__ msg, const int* __restrict__ off,
    const int* __restrict__ cnt, float* __restrict__ h,
    const float* __restrict__ rW, const float* __restrict__ rb,
    float* __restrict__ stats, int* __restrict__ done,
    const float* __restrict__ gw, const float* __restrict__ gb,
    const float* __restrict__ gms, const float* __restrict__ tW,
    const float* __restrict__ tb) {
  __shared__ float Wr[kH * kH];          // 4 KB
  __shared__ float Wt[2 * kH * kH];      // 8 KB
  __shared__ float rbl[kH], tbl[kH], gwl[kH], gbl[kH], gmsl[kH];
  __shared__ float buf[256 * (kH + 1)];  // 33 KB padded
  __shared__ float meanl[kH], rstdl[kH];
  const int tid = threadIdx.x;
  {
    const float4* Ws = reinterpret_cast<const float4*>(rW);
    float4* Wd = reinterpret_cast<float4*>(Wr);
    if (tid < kH * kH / 4) Wd[tid] = Ws[tid];
  }
  {
    const float4* Ws = reinterpret_cast<const float4*>(tW);
    float4* Wd = reinterpret_cast<float4*>(Wt);
    for (int j = tid; j < 2 * kH * kH / 4; j += 256) Wd[j] = Ws[j];
  }
  if (tid < kH) {
    rbl[tid] = rb[tid];
    tbl[tid] = tb[tid];
    gwl[tid] = gw[tid];
    gbl[tid] = gb[tid];
    gmsl[tid] = gms[tid];
  }
  __syncthreads();
  const int node = blockIdx.x * 256 + tid;
  const bool act = node < kN;
  float hr[kH], acc[kH];
#pragma unroll
  for (int o = 0; o < kH; ++o) { acc[o] = 0.f; hr[o] = 0.f; }
  if (act) {
#pragma unroll
    for (int o = 0; o < kH; ++o) acc[o] = rbl[o];
    const int s = off[node], c = cnt[node];
    for (int j = 0; j < c; ++j) {
      const float4* mp =
          reinterpret_cast<const float4*>(msg + (size_t)(s + j) * kH);
#pragma unroll
      for (int o4 = 0; o4 < kH / 4; ++o4) {
        float4 v = mp[o4];
        acc[o4 * 4 + 0] += v.x; acc[o4 * 4 + 1] += v.y;
        acc[o4 * 4 + 2] += v.z; acc[o4 * 4 + 3] += v.w;
      }
    }
    const float4* hp = reinterpret_cast<const float4*>(h + (size_t)node * kH);
#pragma unroll
    for (int i4 = 0; i4 < kH / 4; ++i4) {
      float4 v = hp[i4];
      hr[i4 * 4 + 0] = v.x; hr[i4 * 4 + 1] = v.y;
      hr[i4 * 4 + 2] = v.z; hr[i4 * 4 + 3] = v.w;
    }
#pragma unroll
    for (int o = 0; o < kH; ++o) {
      float a = acc[o];
#pragma unroll
      for (int i = 0; i < kH; ++i) a = fmaf(hr[i], Wr[i * kH + o], a);
      acc[o] = a;
    }
  }
#pragma unroll
  for (int o = 0; o < kH; ++o) buf[tid * (kH + 1) + o] = act ? acc[o] : 0.f;
  __syncthreads();
  if (tid < kH) {
    float s = 0.f, q = 0.f;
#pragma unroll 8
    for (int r = 0; r < 256; ++r) {
      float v = buf[r * (kH + 1) + tid];
      s += v;
      q = fmaf(v, v, q);
    }
    atomicAdd(stats + tid, s);
    atomicAdd(stats + kH + tid, q);
  }
  __syncthreads();   // drains all outstanding stats atomics (vmcnt before barrier)
  __threadfence();
  if (tid == 0) {
    __hip_atomic_fetch_add(done, 1, __ATOMIC_ACQ_REL,
                           __HIP_MEMORY_SCOPE_AGENT);
    while (__hip_atomic_load(done, __ATOMIC_ACQUIRE,
                             __HIP_MEMORY_SCOPE_AGENT) < (int)gridDim.x) {
      __builtin_amdgcn_s_sleep(8);
    }
  }
  __syncthreads();
  if (tid < kH) {
    float s = __hip_atomic_load(&stats[tid], __ATOMIC_RELAXED,
                                __HIP_MEMORY_SCOPE_AGENT);
    float q = __hip_atomic_load(&stats[kH + tid], __ATOMIC_RELAXED,
                                __HIP_MEMORY_SCOPE_AGENT);
    float m = s * (1.f / kN);
    float qq = q * (1.f / kN);
    float msv = gmsl[tid];
    float var = qq - m * m * msv * (2.f - msv);
    meanl[tid] = msv * m;
    rstdl[tid] = rsqrtf(var + kEps);
  }
  __syncthreads();
  if (act) {
    float hc[kH];
#pragma unroll
    for (int o = 0; o < kH; ++o)
      hc[o] = fmaxf((acc[o] - meanl[o]) * rstdl[o] * gwl[o] + gbl[o], 0.f) +
              hr[o];
    float* hw = h + (size_t)node * kH;
#pragma unroll
    for (int o = 0; o < kH; ++o) {
      float a = tbl[o];
#pragma unroll
      for (int k = 0; k < kH; ++k) {
        a = fmaf(hr[k], Wt[k * kH + o], a);
        a = fmaf(hc[k], Wt[(kH + k) * kH + o], a);
      }
      hw[o] = fmaxf(a, 0.f);
    }
  }
}

// ==== FUSED final: linear+stats | spin-sync | graphnorm+relu ====
// grid 313 x 64; all blocks co-resident (25 KB LDS -> 6 blocks/CU, need 53 CUs)
__global__ __launch_bounds__(64) void final_fused(
    const float* __restrict__ h, const float* __restrict__ W,
    const float* __restrict__ b, float* __restrict__ stats,
    int* __restrict__ done, const float* __restrict__ gw,
    const float* __restrict__ gb, const float* __restrict__ gms,
    float* __restrict__ out) {
  __shared__ float Wl[kH * kT];          // 8 KB
  __shared__ float bl[kT];
  __shared__ float buf[64 * (kT + 1)];   // 16.6 KB padded
  __shared__ float meanl[kT], rstdl[kT], wl2[kT], bl2[kT];
  const int tid = threadIdx.x;
  {
    const float4* Ws = reinterpret_cast<const float4*>(W);
    float4* Wd = reinterpret_cast<float4*>(Wl);
    for (int j = tid; j < kH * kT / 4; j += 64) Wd[j] = Ws[j];
  }
  if (tid < kT) bl[tid] = b[tid];
  __syncthreads();
  const int node = blockIdx.x * 64 + tid;
  const bool act = node < kN;
  float hr[kH], ov[kT];
#pragma unroll
  for (int i = 0; i < kH; ++i) hr[i] = 0.f;
  if (act) {
    const float4* hp = reinterpret_cast<const float4*>(h + (size_t)node * kH);
#pragma unroll
    for (int i4 = 0; i4 < kH / 4; ++i4) {
      float4 v = hp[i4];
      hr[i4 * 4 + 0] = v.x; hr[i4 * 4 + 1] = v.y;
      hr[i4 * 4 + 2] = v.z; hr[i4 * 4 + 3] = v.w;
    }
  }
#pragma unroll
  for (int o = 0; o < kT; ++o) {
    float a = act ? bl[o] : 0.f;
#pragma unroll
    for (int i = 0; i < kH; ++i) a = fmaf(hr[i], Wl[i * kT + o], a);
    ov[o] = act ? a : 0.f;
    buf[tid * (kT + 1) + o] = ov[o];
  }
  __syncthreads();
  {
    float s = 0.f, q = 0.f;
#pragma unroll 8
    for (int r = 0; r < 64; ++r) {
      float v = buf[r * (kT + 1) + tid];
      s += v;
      q = fmaf(v, v, q);
    }
    atomicAdd(stats + tid, s);
    atomicAdd(stats + kT + tid, q);
  }
  __syncthreads();
  __threadfence();
  if (tid == 0) {
    __hip_atomic_fetch_add(done, 1, __ATOMIC_ACQ_REL,
                           __HIP_MEMORY_SCOPE_AGENT);
    while (__hip_atomic_load(done, __ATOMIC_ACQUIRE,
                             __HIP_MEMORY_SCOPE_AGENT) < (int)gridDim.x) {
      __builtin_amdgcn_s_sleep(8);
    }
  }
  __syncthreads();
  {
    float s = __hip_atomic_load(&stats[tid], __ATOMIC_RELAXED,
                                __HIP_MEMORY_SCOPE_AGENT);
    float q = __hip_atomic_load(&stats[kT + tid], __ATOMIC_RELAXED,
                                __HIP_MEMORY_SCOPE_AGENT);
    float m = s * (1.f / kN);
    float qq = q * (1.f / kN);
    float msv = gms[tid];
    float var = qq - m * m * msv * (2.f - msv);
    meanl[tid] = msv * m;
    rstdl[tid] = rsqrtf(var + kEps);
    wl2[tid] = gw[tid];
    bl2[tid] = gb[tid];
  }
  __syncthreads();
  if (act) {
    float* op = out + (size_t)node * kT;
#pragma unroll
    for (int o4 = 0; o4 < kT / 4; ++o4) {
      float r[4];
#pragma unroll
      for (int j = 0; j < 4; ++j) {
        const int o = o4 * 4 + j;
        r[j] = fmaxf((ov[o] - meanl[o]) * rstdl[o] * wl2[o] + bl2[o], 0.f);
      }
      *reinterpret_cast<float4*>(op + o4 * 4) =
          make_float4(r[0], r[1], r[2], r[3]);
    }
  }
}

}  // namespace

extern "C" void kernel_launch(void* const* d_in, const int* in_sizes, int n_in,
                              void* d_out, int out_size, void* d_ws,
                              size_t ws_size, hipStream_t stream) {
  const float* x     = (const float*)d_in[0];
  const float* eattr = (const float*)d_in[1];
  const int*   eidx  = (const int*)d_in[2];
  const float* initW = (const float*)d_in[3];
  const float* initb = (const float*)d_in[4];
  const float* emW   = (const float*)d_in[5];
  const float* emb   = (const float*)d_in[6];
  const float* rW    = (const float*)d_in[7];
  const float* rb    = (const float*)d_in[8];
  const float* gnw   = (const float*)d_in[9];
  const float* gnb   = (const float*)d_in[10];
  const float* gnms  = (const float*)d_in[11];
  const float* tW    = (const float*)d_in[12];
  const float* tb    = (const float*)d_in[13];
  const float* fW    = (const float*)d_in[14];
  const float* fb    = (const float*)d_in[15];
  const float* fgw   = (const float*)d_in[16];
  const float* fgb   = (const float*)d_in[17];
  const float* fgms  = (const float*)d_in[18];
  float* out = (float*)d_out;

  // workspace layout: stats | done | cnt contiguous -> single memset
  float* h     = (float*)d_ws;                       // kN*kH f32
  float* msg   = h + (size_t)kN * kH;                // kE*kH f32
  unsigned short* wbf = (unsigned short*)(msg + (size_t)kE * kH);  // 196 KB
  float* stats = (float*)(wbf + (size_t)kL * 64 * 64 * 8);  // 512 f32
  int* done   = (int*)(stats + 512);                 // 16 ints (4 used)
  int* cnt    = done + 16;                           // kN
  int* off    = cnt + kN;                            // kN
  int* rank   = off + kN;                            // kE

  const int node64  = (kN + 63) / 64;                // 313
  const int node256 = (kN + 255) / 256;              // 79
  const int edgeBlocks = kE / 64;                    // 1250 (4 waves x 16 edges)

  // single memset covers stats (512 f32) + done (16) + cnt (kN), contiguous
  hipMemsetAsync(stats, 0, (512 + 16 + kN) * sizeof(float), stream);
  pack_w<<<kL * 64 * 64 / 256, 256, 0, stream>>>(emW, wbf);
  init_proj<<<node64, 64, 0, stream>>>(x, initW, initb, h);
  hist_dst<<<(kE + 255) / 256, 256, 0, stream>>>(eidx, cnt, rank);
  scan_nodes<<<1, 1024, 0, stream>>>(cnt, off);

  for (int l = 0; l < kL; ++l) {
    edge_msg_mfma<<<edgeBlocks, 256, 0, stream>>>(
        eattr, eidx, off, rank, h, wbf + (size_t)l * 64 * 64 * 8,
        emb + (size_t)l * kH * kH, msg);
    layer_fused<<<node256, 256, 0, stream>>>(
        msg, off, cnt, h, rW + (size_t)l * kH * kH, rb + l * kH,
        stats + l * 128, done + l, gnw + l * kH, gnb + l * kH, gnms + l * kH,
        tW + (size_t)l * 2 * kH * kH, tb + l * kH);
  }
  final_fused<<<node64, 64, 0, stream>>>(h, fW, fb, stats + 3 * 128, done + 3,
                                         fgw, fgb, fgms, out);
}

// Round 17
// 227.365 us; speedup vs baseline: 1.1242x; 1.1242x over previous
//
#include <hip/hip_runtime.h>

namespace {

constexpr int kN  = 20000;
constexpr int kE  = 80000;
constexpr int kIn = 64;
constexpr int kH  = 32;
constexpr int kEA = 32;
constexpr int kT  = 64;
constexpr int kL  = 3;
constexpr float kEps = 1e-5f;

typedef __attribute__((ext_vector_type(8))) short bf16x8;
typedef __attribute__((ext_vector_type(4))) float f32x4;

__device__ inline unsigned short f2bf(float f) {
  unsigned u = __builtin_bit_cast(unsigned, f);
  unsigned r = (u + 0x7fff + ((u >> 16) & 1)) >> 16;  // RNE
  return (unsigned short)r;
}
__device__ inline float bf2f(unsigned short s) {
  unsigned u = ((unsigned)s) << 16;
  return __builtin_bit_cast(float, u);
}

// ---- hist + per-edge rank within destination (rank trick: old count) ----
__global__ __launch_bounds__(256) void hist_dst(const int* __restrict__ ei,
                                                int* __restrict__ cnt,
                                                int* __restrict__ rank) {
  const int e = blockIdx.x * 256 + threadIdx.x;
  if (e < kE) rank[e] = atomicAdd(&cnt[ei[kE + e]], 1);
}

// 1 block, 1024 threads; 20 elems/thread serial + wave shfl-scan + wave combine
__global__ __launch_bounds__(1024) void scan_nodes(const int* __restrict__ cnt,
                                                   int* __restrict__ off) {
  __shared__ int wsum[16];
  __shared__ int woff[16];
  const int tid = threadIdx.x, lane = tid & 63, wid = tid >> 6;
  constexpr int CH = 20;  // 1024*20 = 20480 >= kN
  const int base = tid * CH;
  int v[CH];
  int s = 0;
#pragma unroll
  for (int j = 0; j < CH; ++j) {
    const int i = base + j;
    const int c = (i < kN) ? cnt[i] : 0;
    v[j] = s;
    s += c;
  }
  int x = s;
#pragma unroll
  for (int d = 1; d < 64; d <<= 1) {
    int y = __shfl_up(x, d);
    if (lane >= d) x += y;
  }
  if (lane == 63) wsum[wid] = x;
  __syncthreads();
  if (tid < 16) {
    int t = wsum[tid];
    int xx = t;
#pragma unroll
    for (int d = 1; d < 16; d <<= 1) {
      int y = __shfl_up(xx, d);
      if (tid >= d) xx += y;
    }
    woff[tid] = xx - t;
  }
  __syncthreads();
  const int thrbase = woff[wid] + (x - s);
#pragma unroll
  for (int j = 0; j < CH; ++j) {
    const int i = base + j;
    if (i < kN) off[i] = thrbase + v[j];
  }
}

// ---- pack Wm[l] f32[32][1024] -> B-fragment-ordered bf16: frag[l][ct][lane][8]
__global__ __launch_bounds__(256) void pack_w(const float* __restrict__ emW,
                                              unsigned short* __restrict__ wbf) {
  const int idx = blockIdx.x * 256 + threadIdx.x;
  if (idx >= kL * 64 * 64) return;
  const int lane = idx & 63, ct = (idx >> 6) & 63, l = idx >> 12;
  const int k0 = (lane >> 4) * 8, c = ct * 16 + (lane & 15);
  const float* W = emW + (size_t)l * kEA * kH * kH;
  unsigned out[4];
#pragma unroll
  for (int p = 0; p < 4; ++p) {
    unsigned lo = f2bf(W[(size_t)(k0 + 2 * p) * (kH * kH) + c]);
    unsigned hi = f2bf(W[(size_t)(k0 + 2 * p + 1) * (kH * kH) + c]);
    out[p] = lo | (hi << 16);
  }
  *reinterpret_cast<uint4*>(wbf + (size_t)idx * 8) =
      make_uint4(out[0], out[1], out[2], out[3]);
}

// ---------------- h = x @ initW + initb (64-thr blocks) ----------------
__global__ __launch_bounds__(64) void init_proj(
    const float* __restrict__ x, const float* __restrict__ W,
    const float* __restrict__ b, float* __restrict__ h) {
  __shared__ float Wl[kIn * kH];
  __shared__ float bl[kH];
  const int tid = threadIdx.x;
  {
    const float4* Ws = reinterpret_cast<const float4*>(W);
    float4* Wd = reinterpret_cast<float4*>(Wl);
    for (int j = tid; j < kIn * kH / 4; j += 64) Wd[j] = Ws[j];
  }
  if (tid < kH) bl[tid] = b[tid];
  __syncthreads();
  const int node = blockIdx.x * 64 + tid;
  if (node >= kN) return;
  float xr[kIn];
  const float4* xp = reinterpret_cast<const float4*>(x + (size_t)node * kIn);
#pragma unroll
  for (int k4 = 0; k4 < kIn / 4; ++k4) {
    float4 v = xp[k4];
    xr[k4 * 4 + 0] = v.x; xr[k4 * 4 + 1] = v.y;
    xr[k4 * 4 + 2] = v.z; xr[k4 * 4 + 3] = v.w;
  }
  float* hp = h + (size_t)node * kH;
#pragma unroll
  for (int o = 0; o < kH; ++o) {
    float acc = bl[o];
#pragma unroll
    for (int k = 0; k < kIn; ++k) acc = fmaf(xr[k], Wl[k * kH + o], acc);
    hp[o] = acc;
  }
}

// ------- wave-independent MFMA edge MLP: 1 wave = 16 edges, all i -------
// block = 256 thr (4 waves), grid = kE/64 = 1250; ONE barrier (bias staging).
constexpr int HP  = 40;  // h LDS row pitch in ushorts (80 B)
constexpr int MPW = 36;  // msg LDS row pitch in f32 (144 B)
__global__ __launch_bounds__(256) void edge_msg_mfma(
    const float* __restrict__ attr, const int* __restrict__ ei,
    const int* __restrict__ off, const int* __restrict__ rank,
    const float* __restrict__ h, const unsigned short* __restrict__ wbf,
    const float* __restrict__ bm, float* __restrict__ msg_buf) {
  __shared__ float bml[kH * kH];               // 4 KB, block-shared
  __shared__ unsigned short hbuf[4][16 * HP];  // 4 x 1.25 KB, wave-private
  __shared__ float mbuf[4][16 * MPW];          // 4 x 2.25 KB, wave-private
  const int tid = threadIdx.x;
  const int wv = tid >> 6, lane = tid & 63;
  const int lr = lane & 15, lg = lane >> 4;
  const int base = (blockIdx.x * 4 + wv) * 16;  // this wave's 16 edges

  for (int j = tid; j < kH * kH; j += 256) bml[j] = bm[j];

  // A into registers: lane holds attr[base+lr][lg*8 .. +8) as bf16x8
  bf16x8 Af;
  {
    const float4* ap = reinterpret_cast<const float4*>(
        attr + (size_t)(base + lr) * kEA + lg * 8);
    float4 a0 = ap[0], a1 = ap[1];
    Af[0] = (short)f2bf(a0.x); Af[1] = (short)f2bf(a0.y);
    Af[2] = (short)f2bf(a0.z); Af[3] = (short)f2bf(a0.w);
    Af[4] = (short)f2bf(a1.x); Af[5] = (short)f2bf(a1.y);
    Af[6] = (short)f2bf(a1.z); Af[7] = (short)f2bf(a1.w);
  }

  // h into wave-private LDS: lane stages edge base+(lane>>2), cols (lane&3)*8..+8
  {
    const int er = lane >> 2, q = lane & 3;
    const int src = ei[base + er];
    const float4* hp4 =
        reinterpret_cast<const float4*>(h + (size_t)src * kH + q * 8);
    float4 h0 = hp4[0], h1 = hp4[1];
    uint2 p0 = make_uint2(f2bf(h0.x) | ((unsigned)f2bf(h0.y) << 16),
                          f2bf(h0.z) | ((unsigned)f2bf(h0.w) << 16));
    uint2 p1 = make_uint2(f2bf(h1.x) | ((unsigned)f2bf(h1.y) << 16),
                          f2bf(h1.z) | ((unsigned)f2bf(h1.w) << 16));
    *reinterpret_cast<uint2*>(&hbuf[wv][0] + er * HP + q * 8) = p0;
    *reinterpret_cast<uint2*>(&hbuf[wv][0] + er * HP + q * 8 + 4) = p1;
  }

  __syncthreads();  // bml ready (hbuf is wave-private; barrier covers it too)

  float ma[4][2] = {{0.f, 0.f}, {0.f, 0.f}, {0.f, 0.f}, {0.f, 0.f}};
  const unsigned short* hrow = &hbuf[wv][0];

#pragma unroll
  for (int g = 0; g < 4; ++g) {  // il groups of 8
    bf16x8 hv0 = *reinterpret_cast<const bf16x8*>(hrow + (lg * 4 + 0) * HP + g * 8);
    bf16x8 hv1 = *reinterpret_cast<const bf16x8*>(hrow + (lg * 4 + 1) * HP + g * 8);
    bf16x8 hv2 = *reinterpret_cast<const bf16x8*>(hrow + (lg * 4 + 2) * HP + g * 8);
    bf16x8 hv3 = *reinterpret_cast<const bf16x8*>(hrow + (lg * 4 + 3) * HP + g * 8);
#pragma unroll
    for (int i8 = 0; i8 < 8; ++i8) {
      const int il = g * 8 + i8;
      bf16x8 B0 = *reinterpret_cast<const bf16x8*>(
          wbf + ((size_t)(il * 2 + 0) * 64 + lane) * 8);
      bf16x8 B1 = *reinterpret_cast<const bf16x8*>(
          wbf + ((size_t)(il * 2 + 1) * 64 + lane) * 8);
      const float b0 = bml[il * kH + lr];
      const float b1 = bml[il * kH + 16 + lr];
      f32x4 c0, c1;
      c0[0] = b0; c0[1] = b0; c0[2] = b0; c0[3] = b0;
      c1[0] = b1; c1[1] = b1; c1[2] = b1; c1[3] = b1;
      c0 = __builtin_amdgcn_mfma_f32_16x16x32_bf16(Af, B0, c0, 0, 0, 0);
      c1 = __builtin_amdgcn_mfma_f32_16x16x32_bf16(Af, B1, c1, 0, 0, 0);
      const float h0 = bf2f((unsigned short)hv0[i8]);
      const float h1 = bf2f((unsigned short)hv1[i8]);
      const float h2 = bf2f((unsigned short)hv2[i8]);
      const float h3 = bf2f((unsigned short)hv3[i8]);
      ma[0][0] = fmaf(fmaxf(c0[0], 0.f), h0, ma[0][0]);
      ma[1][0] = fmaf(fmaxf(c0[1], 0.f), h1, ma[1][0]);
      ma[2][0] = fmaf(fmaxf(c0[2], 0.f), h2, ma[2][0]);
      ma[3][0] = fmaf(fmaxf(c0[3], 0.f), h3, ma[3][0]);
      ma[0][1] = fmaf(fmaxf(c1[0], 0.f), h0, ma[0][1]);
      ma[1][1] = fmaf(fmaxf(c1[1], 0.f), h1, ma[1][1]);
      ma[2][1] = fmaf(fmaxf(c1[2], 0.f), h2, ma[2][1]);
      ma[3][1] = fmaf(fmaxf(c1[3], 0.f), h3, ma[3][1]);
    }
  }

  // epilogue: wave-private LDS transpose -> coalesced float4 stores
  float* mrow = &mbuf[wv][0];
#pragma unroll
  for (int r = 0; r < 4; ++r) {
    mrow[(lg * 4 + r) * MPW + lr] = ma[r][0];
    mrow[(lg * 4 + r) * MPW + 16 + lr] = ma[r][1];
  }
  // same-wave LDS RAW: compiler inserts lgkmcnt; no barrier needed
  {
    const int er = lane >> 2, q = lane & 3;
    const int e = base + er;
    const int mp = off[ei[kE + e]] + rank[e];
    float4 v0 = *reinterpret_cast<const float4*>(mrow + er * MPW + q * 8);
    float4 v1 = *reinterpret_cast<const float4*>(mrow + er * MPW + q * 8 + 4);
    float* orow = msg_buf + (size_t)mp * kH + q * 8;
    *reinterpret_cast<float4*>(orow) = v0;
    *reinterpret_cast<float4*>(orow + 4) = v1;
  }
}

// --- conv = segsum(msg) + h@rootW + rootb; 64-thr blocks, grid 313 ---
__global__ __launch_bounds__(64) void agg_root_stats(
    const float* __restrict__ msg, const int* __restrict__ off,
    const int* __restrict__ cnt, const float* __restrict__ h,
    const float* __restrict__ W, const float* __restrict__ b,
    float* __restrict__ conv, float* __restrict__ stats) {
  __shared__ float Wl[kH * kH];         // 4 KB
  __shared__ float bl[kH];
  __shared__ float buf[64 * (kH + 1)];  // 8.25 KB padded
  const int tid = threadIdx.x;
  {
    const float4* Ws = reinterpret_cast<const float4*>(W);
    float4* Wd = reinterpret_cast<float4*>(Wl);
    for (int j = tid; j < kH * kH / 4; j += 64) Wd[j] = Ws[j];
  }
  if (tid < kH) bl[tid] = b[tid];
  __syncthreads();
  const int node = blockIdx.x * 64 + tid;
  const bool act = node < kN;
  float acc[kH];
#pragma unroll
  for (int o = 0; o < kH; ++o) acc[o] = 0.f;
  if (act) {
#pragma unroll
    for (int o = 0; o < kH; ++o) acc[o] = bl[o];
    const int s = off[node], c = cnt[node];
    for (int j = 0; j < c; ++j) {
      const float4* mp =
          reinterpret_cast<const float4*>(msg + (size_t)(s + j) * kH);
#pragma unroll
      for (int o4 = 0; o4 < kH / 4; ++o4) {
        float4 v = mp[o4];
        acc[o4 * 4 + 0] += v.x; acc[o4 * 4 + 1] += v.y;
        acc[o4 * 4 + 2] += v.z; acc[o4 * 4 + 3] += v.w;
      }
    }
    float hr[kH];
    const float4* hp = reinterpret_cast<const float4*>(h + (size_t)node * kH);
#pragma unroll
    for (int i4 = 0; i4 < kH / 4; ++i4) {
      float4 v = hp[i4];
      hr[i4 * 4 + 0] = v.x; hr[i4 * 4 + 1] = v.y;
      hr[i4 * 4 + 2] = v.z; hr[i4 * 4 + 3] = v.w;
    }
#pragma unroll
    for (int o = 0; o < kH; ++o) {
      float a = acc[o];
#pragma unroll
      for (int i = 0; i < kH; ++i) a = fmaf(hr[i], Wl[i * kH + o], a);
      acc[o] = a;
    }
    float* cp = conv + (size_t)node * kH;
#pragma unroll
    for (int o4 = 0; o4 < kH / 4; ++o4)
      *reinterpret_cast<float4*>(cp + o4 * 4) =
          make_float4(acc[o4 * 4], acc[o4 * 4 + 1], acc[o4 * 4 + 2],
                      acc[o4 * 4 + 3]);
  }
#pragma unroll
  for (int o = 0; o < kH; ++o) buf[tid * (kH + 1) + o] = act ? acc[o] : 0.f;
  __syncthreads();
  if (tid < kH) {
    float s = 0.f, q = 0.f;
#pragma unroll 8
    for (int r = 0; r < 64; ++r) {
      float v = buf[r * (kH + 1) + tid];
      s += v;
      q = fmaf(v, v, q);
    }
    atomicAdd(stats + tid, s);
    atomicAdd(stats + kH + tid, q);
  }
}

// ---- hc = relu(graphnorm(conv))+h ; h = relu([h,hc]@transW + tb) (64-thr) ----
__global__ __launch_bounds__(64) void norm_trans(
    const float* __restrict__ conv, const float* __restrict__ stats,
    const float* __restrict__ gw, const float* __restrict__ gb,
    const float* __restrict__ gms, const float* __restrict__ Wt,
    const float* __restrict__ tb, float* __restrict__ h) {
  __shared__ float Wl[2 * kH * kH];
  __shared__ float tbl[kH];
  __shared__ float meanl[kH], rstdl[kH], gwl[kH], gbl[kH];
  const int tid = threadIdx.x;
  {
    const float4* Ws = reinterpret_cast<const float4*>(Wt);
    float4* Wd = reinterpret_cast<float4*>(Wl);
    for (int j = tid; j < 2 * kH * kH / 4; j += 64) Wd[j] = Ws[j];
  }
  if (tid < kH) {
    tbl[tid] = tb[tid];
    float m = stats[tid] * (1.f / kN);
    float q = stats[kH + tid] * (1.f / kN);
    float msv = gms[tid];
    float var = q - m * m * msv * (2.f - msv);
    meanl[tid] = msv * m;
    rstdl[tid] = rsqrtf(var + kEps);
    gwl[tid] = gw[tid];
    gbl[tid] = gb[tid];
  }
  __syncthreads();
  const int node = blockIdx.x * 64 + tid;
  if (node >= kN) return;
  float in_[2 * kH];
  const float* hp = h + (size_t)node * kH;
  const float* cp = conv + (size_t)node * kH;
#pragma unroll
  for (int i = 0; i < kH; ++i) in_[i] = hp[i];
#pragma unroll
  for (int o = 0; o < kH; ++o) {
    float v = cp[o];
    in_[kH + o] =
        fmaxf((v - meanl[o]) * rstdl[o] * gwl[o] + gbl[o], 0.f) + in_[o];
  }
  float* hw = h + (size_t)node * kH;
#pragma unroll
  for (int o = 0; o < kH; ++o) {
    float acc = tbl[o];
#pragma unroll
    for (int k = 0; k < 2 * kH; ++k) acc = fmaf(in_[k], Wl[k * kH + o], acc);
    hw[o] = fmaxf(acc, 0.f);
  }
}

// ---------- out = h @ finalW + finalb (+ stats), 64-thr blocks ----------
__global__ __launch_bounds__(64) void final_lin(
    const float* __restrict__ h, const float* __restrict__ W,
    const float* __restrict__ b, float* __restrict__ out,
    float* __restrict__ stats) {
  __shared__ float Wl[kH * kT];
  __shared__ float bl[kT];
  __shared__ float buf[64 * (kT + 1)];
  const int tid = threadIdx.x;
  {
    const float4* Ws = reinterpret_cast<const float4*>(W);
    float4* Wd = reinterpret_cast<float4*>(Wl);
    for (int j = tid; j < kH * kT / 4; j += 64) Wd[j] = Ws[j];
  }
  if (tid < kT) bl[tid] = b[tid];
  __syncthreads();
  const int node = blockIdx.x * 64 + tid;
  const bool act = node < kN;
  float hr[kH];
  if (act) {
    const float4* hp = reinterpret_cast<const float4*>(h + (size_t)node * kH);
#pragma unroll
    for (int i4 = 0; i4 < kH / 4; ++i4) {
      float4 v = hp[i4];
      hr[i4 * 4 + 0] = v.x; hr[i4 * 4 + 1] = v.y;
      hr[i4 * 4 + 2] = v.z; hr[i4 * 4 + 3] = v.w;
    }
  } else {
#pragma unroll
    for (int i = 0; i < kH; ++i) hr[i] = 0.f;
  }
  float* op = out + (size_t)node * kT;
#pragma unroll
  for (int o = 0; o < kT; ++o) {
    float acc = 0.f;
    if (act) {
      acc = bl[o];
#pragma unroll
      for (int i = 0; i < kH; ++i) acc = fmaf(hr[i], Wl[i * kT + o], acc);
      op[o] = acc;
    }
    buf[tid * (kT + 1) + o] = act ? acc : 0.f;
  }
  __syncthreads();
  if (tid < kT) {
    float s = 0.f, q = 0.f;
#pragma unroll 8
    for (int r = 0; r < 64; ++r) {
      float v = buf[r * (kT + 1) + tid];
      s += v;
      q = fmaf(v, v, q);
    }
    atomicAdd(stats + tid, s);
    atomicAdd(stats + kT + tid, q);
  }
}

// ------------- final graphnorm + relu (in place, 64-thr blocks) -------------
__global__ __launch_bounds__(64) void final_norm(
    const float* __restrict__ stats, const float* __restrict__ w,
    const float* __restrict__ b, const float* __restrict__ ms,
    float* __restrict__ out) {
  __shared__ float meanl[kT], rstdl[kT], wl2[kT], bl2[kT];
  const int tid = threadIdx.x;
  if (tid < kT) {
    float m = stats[tid] * (1.f / kN);
    float q = stats[kT + tid] * (1.f / kN);
    float msv = ms[tid];
    float var = q - m * m * msv * (2.f - msv);
    meanl[tid] = msv * m;
    rstdl[tid] = rsqrtf(var + kEps);
    wl2[tid] = w[tid];
    bl2[tid] = b[tid];
  }
  __syncthreads();
  const int node = blockIdx.x * 64 + tid;
  if (node >= kN) return;
  float* op = out + (size_t)node * kT;
#pragma unroll
  for (int o4 = 0; o4 < kT / 4; ++o4) {
    float4 v = *reinterpret_cast<const float4*>(op + o4 * 4);
    float r[4] = {v.x, v.y, v.z, v.w};
#pragma unroll
    for (int j = 0; j < 4; ++j) {
      int o = o4 * 4 + j;
      r[j] = fmaxf((r[j] - meanl[o]) * rstdl[o] * wl2[o] + bl2[o], 0.f);
    }
    *reinterpret_cast<float4*>(op + o4 * 4) =
        make_float4(r[0], r[1], r[2], r[3]);
  }
}

}  // namespace

extern "C" void kernel_launch(void* const* d_in, const int* in_sizes, int n_in,
                              void* d_out, int out_size, void* d_ws,
                              size_t ws_size, hipStream_t stream) {
  const float* x     = (const float*)d_in[0];
  const float* eattr = (const float*)d_in[1];
  const int*   eidx  = (const int*)d_in[2];
  const float* initW = (const float*)d_in[3];
  const float* initb = (const float*)d_in[4];
  const float* emW   = (const float*)d_in[5];
  const float* emb   = (const float*)d_in[6];
  const float* rW    = (const float*)d_in[7];
  const float* rb    = (const float*)d_in[8];
  const float* gnw   = (const float*)d_in[9];
  const float* gnb   = (const float*)d_in[10];
  const float* gnms  = (const float*)d_in[11];
  const float* tW    = (const float*)d_in[12];
  const float* tb    = (const float*)d_in[13];
  const float* fW    = (const float*)d_in[14];
  const float* fb    = (const float*)d_in[15];
  const float* fgw   = (const float*)d_in[16];
  const float* fgb   = (const float*)d_in[17];
  const float* fgms  = (const float*)d_in[18];
  float* out = (float*)d_out;

  // workspace layout (stats adjacent to cnt -> single memset for both)
  float* h     = (float*)d_ws;                       // kN*kH f32
  float* conv  = h + (size_t)kN * kH;                // kN*kH f32
  float* msg   = conv + (size_t)kN * kH;             // kE*kH f32
  unsigned short* wbf = (unsigned short*)(msg + (size_t)kE * kH);  // 196 KB
  float* stats = (float*)(wbf + (size_t)kL * 64 * 64 * 8);  // 512 f32
  int* cnt    = (int*)(stats + 512);                 // kN
  int* off    = cnt + kN;                            // kN
  int* rank   = off + kN;                            // kE

  const int node64  = (kN + 63) / 64;                // 313
  const int edgeBlocks = kE / 64;                    // 1250 (4 waves x 16 edges)

  // single memset covers stats (512 f32) + cnt (kN ints), contiguous
  hipMemsetAsync(stats, 0, (512 + kN) * sizeof(float), stream);
  pack_w<<<kL * 64 * 64 / 256, 256, 0, stream>>>(emW, wbf);
  init_proj<<<node64, 64, 0, stream>>>(x, initW, initb, h);
  hist_dst<<<(kE + 255) / 256, 256, 0, stream>>>(eidx, cnt, rank);
  scan_nodes<<<1, 1024, 0, stream>>>(cnt, off);

  for (int l = 0; l < kL; ++l) {
    float* st = stats + l * 128;
    edge_msg_mfma<<<edgeBlocks, 256, 0, stream>>>(
        eattr, eidx, off, rank, h, wbf + (size_t)l * 64 * 64 * 8,
        emb + (size_t)l * kH * kH, msg);
    agg_root_stats<<<node64, 64, 0, stream>>>(
        msg, off, cnt, h, rW + (size_t)l * kH * kH, rb + l * kH, conv, st);
    norm_trans<<<node64, 64, 0, stream>>>(
        conv, st, gnw + l * kH, gnb + l * kH, gnms + l * kH,
        tW + (size_t)l * 2 * kH * kH, tb + l * kH, h);
  }
  final_lin<<<node64, 64, 0, stream>>>(h, fW, fb, out, stats + 3 * 128);
  final_norm<<<node64, 64, 0, stream>>>(stats + 3 * 128, fgw, fgb, fgms, out);
}

// Round 18
// 219.899 us; speedup vs baseline: 1.1624x; 1.0340x over previous
//
#include <hip/hip_runtime.h>

namespace {

constexpr int kN  = 20000;
constexpr int kE  = 80000;
constexpr int kIn = 64;
constexpr int kH  = 32;
constexpr int kEA = 32;
constexpr int kT  = 64;
constexpr int kL  = 3;
constexpr float kEps = 1e-5f;

typedef __attribute__((ext_vector_type(8))) short bf16x8;
typedef __attribute__((ext_vector_type(4))) float f32x4;

__device__ inline unsigned short f2bf(float f) {
  unsigned u = __builtin_bit_cast(unsigned, f);
  unsigned r = (u + 0x7fff + ((u >> 16) & 1)) >> 16;  // RNE
  return (unsigned short)r;
}
__device__ inline float bf2f(unsigned short s) {
  unsigned u = ((unsigned)s) << 16;
  return __builtin_bit_cast(float, u);
}

// ---- hist + per-edge rank within destination (rank trick: old count) ----
__global__ __launch_bounds__(256) void hist_dst(const int* __restrict__ ei,
                                                int* __restrict__ cnt,
                                                int* __restrict__ rank) {
  const int e = blockIdx.x * 256 + threadIdx.x;
  if (e < kE) rank[e] = atomicAdd(&cnt[ei[kE + e]], 1);
}

// 1 block, 1024 threads; 20 elems/thread serial + wave shfl-scan + wave combine
__global__ __launch_bounds__(1024) void scan_nodes(const int* __restrict__ cnt,
                                                   int* __restrict__ off) {
  __shared__ int wsum[16];
  __shared__ int woff[16];
  const int tid = threadIdx.x, lane = tid & 63, wid = tid >> 6;
  constexpr int CH = 20;  // 1024*20 = 20480 >= kN
  const int base = tid * CH;
  int v[CH];
  int s = 0;
#pragma unroll
  for (int j = 0; j < CH; ++j) {
    const int i = base + j;
    const int c = (i < kN) ? cnt[i] : 0;
    v[j] = s;
    s += c;
  }
  int x = s;
#pragma unroll
  for (int d = 1; d < 64; d <<= 1) {
    int y = __shfl_up(x, d);
    if (lane >= d) x += y;
  }
  if (lane == 63) wsum[wid] = x;
  __syncthreads();
  if (tid < 16) {
    int t = wsum[tid];
    int xx = t;
#pragma unroll
    for (int d = 1; d < 16; d <<= 1) {
      int y = __shfl_up(xx, d);
      if (tid >= d) xx += y;
    }
    woff[tid] = xx - t;
  }
  __syncthreads();
  const int thrbase = woff[wid] + (x - s);
#pragma unroll
  for (int j = 0; j < CH; ++j) {
    const int i = base + j;
    if (i < kN) off[i] = thrbase + v[j];
  }
}

// ---- pack Wm[l] f32[32][1024] -> B-fragment-ordered bf16: frag[l][ct][lane][8]
__global__ __launch_bounds__(256) void pack_w(const float* __restrict__ emW,
                                              unsigned short* __restrict__ wbf) {
  const int idx = blockIdx.x * 256 + threadIdx.x;
  if (idx >= kL * 64 * 64) return;
  const int lane = idx & 63, ct = (idx >> 6) & 63, l = idx >> 12;
  const int k0 = (lane >> 4) * 8, c = ct * 16 + (lane & 15);
  const float* W = emW + (size_t)l * kEA * kH * kH;
  unsigned out[4];
#pragma unroll
  for (int p = 0; p < 4; ++p) {
    unsigned lo = f2bf(W[(size_t)(k0 + 2 * p) * (kH * kH) + c]);
    unsigned hi = f2bf(W[(size_t)(k0 + 2 * p + 1) * (kH * kH) + c]);
    out[p] = lo | (hi << 16);
  }
  *reinterpret_cast<uint4*>(wbf + (size_t)idx * 8) =
      make_uint4(out[0], out[1], out[2], out[3]);
}

// ---------------- h = x @ initW + initb (64-thr blocks) ----------------
__global__ __launch_bounds__(64) void init_proj(
    const float* __restrict__ x, const float* __restrict__ W,
    const float* __restrict__ b, float* __restrict__ h) {
  __shared__ float Wl[kIn * kH];
  __shared__ float bl[kH];
  const int tid = threadIdx.x;
  {
    const float4* Ws = reinterpret_cast<const float4*>(W);
    float4* Wd = reinterpret_cast<float4*>(Wl);
    for (int j = tid; j < kIn * kH / 4; j += 64) Wd[j] = Ws[j];
  }
  if (tid < kH) bl[tid] = b[tid];
  __syncthreads();
  const int node = blockIdx.x * 64 + tid;
  if (node >= kN) return;
  float xr[kIn];
  const float4* xp = reinterpret_cast<const float4*>(x + (size_t)node * kIn);
#pragma unroll
  for (int k4 = 0; k4 < kIn / 4; ++k4) {
    float4 v = xp[k4];
    xr[k4 * 4 + 0] = v.x; xr[k4 * 4 + 1] = v.y;
    xr[k4 * 4 + 2] = v.z; xr[k4 * 4 + 3] = v.w;
  }
  float* hp = h + (size_t)node * kH;
#pragma unroll
  for (int o = 0; o < kH; ++o) {
    float acc = bl[o];
#pragma unroll
    for (int k = 0; k < kIn; ++k) acc = fmaf(xr[k], Wl[k * kH + o], acc);
    hp[o] = acc;
  }
}

// ------- wave-independent MFMA edge MLP: 1 wave = 16 edges, all i -------
// block = 256 thr (4 waves), grid = kE/64 = 1250; ONE barrier (bias staging).
constexpr int HP  = 40;  // h LDS row pitch in ushorts (80 B)
constexpr int MPW = 36;  // msg LDS row pitch in f32 (144 B)
__global__ __launch_bounds__(256) void edge_msg_mfma(
    const float* __restrict__ attr, const int* __restrict__ ei,
    const int* __restrict__ off, const int* __restrict__ rank,
    const float* __restrict__ h, const unsigned short* __restrict__ wbf,
    const float* __restrict__ bm, float* __restrict__ msg_buf) {
  __shared__ float bml[kH * kH];               // 4 KB, block-shared
  __shared__ unsigned short hbuf[4][16 * HP];  // 4 x 1.25 KB, wave-private
  __shared__ float mbuf[4][16 * MPW];          // 4 x 2.25 KB, wave-private
  const int tid = threadIdx.x;
  const int wv = tid >> 6, lane = tid & 63;
  const int lr = lane & 15, lg = lane >> 4;
  const int base = (blockIdx.x * 4 + wv) * 16;  // this wave's 16 edges

  for (int j = tid; j < kH * kH; j += 256) bml[j] = bm[j];

  // A into registers: lane holds attr[base+lr][lg*8 .. +8) as bf16x8
  bf16x8 Af;
  {
    const float4* ap = reinterpret_cast<const float4*>(
        attr + (size_t)(base + lr) * kEA + lg * 8);
    float4 a0 = ap[0], a1 = ap[1];
    Af[0] = (short)f2bf(a0.x); Af[1] = (short)f2bf(a0.y);
    Af[2] = (short)f2bf(a0.z); Af[3] = (short)f2bf(a0.w);
    Af[4] = (short)f2bf(a1.x); Af[5] = (short)f2bf(a1.y);
    Af[6] = (short)f2bf(a1.z); Af[7] = (short)f2bf(a1.w);
  }

  // h into wave-private LDS: lane stages edge base+(lane>>2), cols (lane&3)*8..+8
  {
    const int er = lane >> 2, q = lane & 3;
    const int src = ei[base + er];
    const float4* hp4 =
        reinterpret_cast<const float4*>(h + (size_t)src * kH + q * 8);
    float4 h0 = hp4[0], h1 = hp4[1];
    uint2 p0 = make_uint2(f2bf(h0.x) | ((unsigned)f2bf(h0.y) << 16),
                          f2bf(h0.z) | ((unsigned)f2bf(h0.w) << 16));
    uint2 p1 = make_uint2(f2bf(h1.x) | ((unsigned)f2bf(h1.y) << 16),
                          f2bf(h1.z) | ((unsigned)f2bf(h1.w) << 16));
    *reinterpret_cast<uint2*>(&hbuf[wv][0] + er * HP + q * 8) = p0;
    *reinterpret_cast<uint2*>(&hbuf[wv][0] + er * HP + q * 8 + 4) = p1;
  }

  __syncthreads();  // bml ready (hbuf is wave-private; barrier covers it too)

  float ma[4][2] = {{0.f, 0.f}, {0.f, 0.f}, {0.f, 0.f}, {0.f, 0.f}};
  const unsigned short* hrow = &hbuf[wv][0];

#pragma unroll
  for (int g = 0; g < 4; ++g) {  // il groups of 8
    bf16x8 hv0 = *reinterpret_cast<const bf16x8*>(hrow + (lg * 4 + 0) * HP + g * 8);
    bf16x8 hv1 = *reinterpret_cast<const bf16x8*>(hrow + (lg * 4 + 1) * HP + g * 8);
    bf16x8 hv2 = *reinterpret_cast<const bf16x8*>(hrow + (lg * 4 + 2) * HP + g * 8);
    bf16x8 hv3 = *reinterpret_cast<const bf16x8*>(hrow + (lg * 4 + 3) * HP + g * 8);
#pragma unroll
    for (int i8 = 0; i8 < 8; ++i8) {
      const int il = g * 8 + i8;
      bf16x8 B0 = *reinterpret_cast<const bf16x8*>(
          wbf + ((size_t)(il * 2 + 0) * 64 + lane) * 8);
      bf16x8 B1 = *reinterpret_cast<const bf16x8*>(
          wbf + ((size_t)(il * 2 + 1) * 64 + lane) * 8);
      const float b0 = bml[il * kH + lr];
      const float b1 = bml[il * kH + 16 + lr];
      f32x4 c0, c1;
      c0[0] = b0; c0[1] = b0; c0[2] = b0; c0[3] = b0;
      c1[0] = b1; c1[1] = b1; c1[2] = b1; c1[3] = b1;
      c0 = __builtin_amdgcn_mfma_f32_16x16x32_bf16(Af, B0, c0, 0, 0, 0);
      c1 = __builtin_amdgcn_mfma_f32_16x16x32_bf16(Af, B1, c1, 0, 0, 0);
      const float h0 = bf2f((unsigned short)hv0[i8]);
      const float h1 = bf2f((unsigned short)hv1[i8]);
      const float h2 = bf2f((unsigned short)hv2[i8]);
      const float h3 = bf2f((unsigned short)hv3[i8]);
      ma[0][0] = fmaf(fmaxf(c0[0], 0.f), h0, ma[0][0]);
      ma[1][0] = fmaf(fmaxf(c0[1], 0.f), h1, ma[1][0]);
      ma[2][0] = fmaf(fmaxf(c0[2], 0.f), h2, ma[2][0]);
      ma[3][0] = fmaf(fmaxf(c0[3], 0.f), h3, ma[3][0]);
      ma[0][1] = fmaf(fmaxf(c1[0], 0.f), h0, ma[0][1]);
      ma[1][1] = fmaf(fmaxf(c1[1], 0.f), h1, ma[1][1]);
      ma[2][1] = fmaf(fmaxf(c1[2], 0.f), h2, ma[2][1]);
      ma[3][1] = fmaf(fmaxf(c1[3], 0.f), h3, ma[3][1]);
    }
  }

  // epilogue: wave-private LDS transpose -> coalesced float4 stores
  float* mrow = &mbuf[wv][0];
#pragma unroll
  for (int r = 0; r < 4; ++r) {
    mrow[(lg * 4 + r) * MPW + lr] = ma[r][0];
    mrow[(lg * 4 + r) * MPW + 16 + lr] = ma[r][1];
  }
  // same-wave LDS RAW: compiler inserts lgkmcnt; no barrier needed
  {
    const int er = lane >> 2, q = lane & 3;
    const int e = base + er;
    const int mp = off[ei[kE + e]] + rank[e];
    float4 v0 = *reinterpret_cast<const float4*>(mrow + er * MPW + q * 8);
    float4 v1 = *reinterpret_cast<const float4*>(mrow + er * MPW + q * 8 + 4);
    float* orow = msg_buf + (size_t)mp * kH + q * 8;
    *reinterpret_cast<float4*>(orow) = v0;
    *reinterpret_cast<float4*>(orow + 4) = v1;
  }
}

// --- conv = segsum(msg) + h@rootW + rootb; stats via padded-LDS transpose ---
__global__ __launch_bounds__(256) void agg_root_stats(
    const float* __restrict__ msg, const int* __restrict__ off,
    const int* __restrict__ cnt, const float* __restrict__ h,
    const float* __restrict__ W, const float* __restrict__ b,
    float* __restrict__ conv, float* __restrict__ stats) {
  __shared__ float Wl[kH * kH];          // 4 KB
  __shared__ float bl[kH];
  __shared__ float buf[256 * (kH + 1)];  // 33 KB padded
  const int tid = threadIdx.x;
  {
    const float4* Ws = reinterpret_cast<const float4*>(W);
    float4* Wd = reinterpret_cast<float4*>(Wl);
    if (tid < kH * kH / 4) Wd[tid] = Ws[tid];
  }
  if (tid < kH) bl[tid] = b[tid];
  __syncthreads();
  const int node = blockIdx.x * 256 + tid;
  const bool act = node < kN;
  float acc[kH];
#pragma unroll
  for (int o = 0; o < kH; ++o) acc[o] = 0.f;
  if (act) {
#pragma unroll
    for (int o = 0; o < kH; ++o) acc[o] = bl[o];
    const int s = off[node], c = cnt[node];
    for (int j = 0; j < c; ++j) {
      const float4* mp =
          reinterpret_cast<const float4*>(msg + (size_t)(s + j) * kH);
#pragma unroll
      for (int o4 = 0; o4 < kH / 4; ++o4) {
        float4 v = mp[o4];
        acc[o4 * 4 + 0] += v.x; acc[o4 * 4 + 1] += v.y;
        acc[o4 * 4 + 2] += v.z; acc[o4 * 4 + 3] += v.w;
      }
    }
    float hr[kH];
    const float4* hp = reinterpret_cast<const float4*>(h + (size_t)node * kH);
#pragma unroll
    for (int i4 = 0; i4 < kH / 4; ++i4) {
      float4 v = hp[i4];
      hr[i4 * 4 + 0] = v.x; hr[i4 * 4 + 1] = v.y;
      hr[i4 * 4 + 2] = v.z; hr[i4 * 4 + 3] = v.w;
    }
#pragma unroll
    for (int o = 0; o < kH; ++o) {
      float a = acc[o];
#pragma unroll
      for (int i = 0; i < kH; ++i) a = fmaf(hr[i], Wl[i * kH + o], a);
      acc[o] = a;
    }
    float* cp = conv + (size_t)node * kH;
#pragma unroll
    for (int o4 = 0; o4 < kH / 4; ++o4)
      *reinterpret_cast<float4*>(cp + o4 * 4) =
          make_float4(acc[o4 * 4], acc[o4 * 4 + 1], acc[o4 * 4 + 2],
                      acc[o4 * 4 + 3]);
  }
#pragma unroll
  for (int o = 0; o < kH; ++o) buf[tid * (kH + 1) + o] = act ? acc[o] : 0.f;
  __syncthreads();
  if (tid < kH) {
    float s = 0.f, q = 0.f;
#pragma unroll 8
    for (int r = 0; r < 256; ++r) {
      float v = buf[r * (kH + 1) + tid];
      s += v;
      q = fmaf(v, v, q);
    }
    atomicAdd(stats + tid, s);
    atomicAdd(stats + kH + tid, q);
  }
}

// ---- hc = relu(graphnorm(conv))+h ; h = relu([h,hc]@transW + tb) (64-thr) ----
__global__ __launch_bounds__(64) void norm_trans(
    const float* __restrict__ conv, const float* __restrict__ stats,
    const float* __restrict__ gw, const float* __restrict__ gb,
    const float* __restrict__ gms, const float* __restrict__ Wt,
    const float* __restrict__ tb, float* __restrict__ h) {
  __shared__ float Wl[2 * kH * kH];
  __shared__ float tbl[kH];
  __shared__ float meanl[kH], rstdl[kH], gwl[kH], gbl[kH];
  const int tid = threadIdx.x;
  {
    const float4* Ws = reinterpret_cast<const float4*>(Wt);
    float4* Wd = reinterpret_cast<float4*>(Wl);
    for (int j = tid; j < 2 * kH * kH / 4; j += 64) Wd[j] = Ws[j];
  }
  if (tid < kH) {
    tbl[tid] = tb[tid];
    float m = stats[tid] * (1.f / kN);
    float q = stats[kH + tid] * (1.f / kN);
    float msv = gms[tid];
    float var = q - m * m * msv * (2.f - msv);
    meanl[tid] = msv * m;
    rstdl[tid] = rsqrtf(var + kEps);
    gwl[tid] = gw[tid];
    gbl[tid] = gb[tid];
  }
  __syncthreads();
  const int node = blockIdx.x * 64 + tid;
  if (node >= kN) return;
  float in_[2 * kH];
  const float* hp = h + (size_t)node * kH;
  const float* cp = conv + (size_t)node * kH;
#pragma unroll
  for (int i = 0; i < kH; ++i) in_[i] = hp[i];
#pragma unroll
  for (int o = 0; o < kH; ++o) {
    float v = cp[o];
    in_[kH + o] =
        fmaxf((v - meanl[o]) * rstdl[o] * gwl[o] + gbl[o], 0.f) + in_[o];
  }
  float* hw = h + (size_t)node * kH;
#pragma unroll
  for (int o = 0; o < kH; ++o) {
    float acc = tbl[o];
#pragma unroll
    for (int k = 0; k < 2 * kH; ++k) acc = fmaf(in_[k], Wl[k * kH + o], acc);
    hw[o] = fmaxf(acc, 0.f);
  }
}

// ---------- out = h @ finalW + finalb (+ stats), 64-thr blocks ----------
__global__ __launch_bounds__(64) void final_lin(
    const float* __restrict__ h, const float* __restrict__ W,
    const float* __restrict__ b, float* __restrict__ out,
    float* __restrict__ stats) {
  __shared__ float Wl[kH * kT];
  __shared__ float bl[kT];
  __shared__ float buf[64 * (kT + 1)];
  const int tid = threadIdx.x;
  {
    const float4* Ws = reinterpret_cast<const float4*>(W);
    float4* Wd = reinterpret_cast<float4*>(Wl);
    for (int j = tid; j < kH * kT / 4; j += 64) Wd[j] = Ws[j];
  }
  if (tid < kT) bl[tid] = b[tid];
  __syncthreads();
  const int node = blockIdx.x * 64 + tid;
  const bool act = node < kN;
  float hr[kH];
  if (act) {
    const float4* hp = reinterpret_cast<const float4*>(h + (size_t)node * kH);
#pragma unroll
    for (int i4 = 0; i4 < kH / 4; ++i4) {
      float4 v = hp[i4];
      hr[i4 * 4 + 0] = v.x; hr[i4 * 4 + 1] = v.y;
      hr[i4 * 4 + 2] = v.z; hr[i4 * 4 + 3] = v.w;
    }
  } else {
#pragma unroll
    for (int i = 0; i < kH; ++i) hr[i] = 0.f;
  }
  float* op = out + (size_t)node * kT;
#pragma unroll
  for (int o = 0; o < kT; ++o) {
    float acc = 0.f;
    if (act) {
      acc = bl[o];
#pragma unroll
      for (int i = 0; i < kH; ++i) acc = fmaf(hr[i], Wl[i * kT + o], acc);
      op[o] = acc;
    }
    buf[tid * (kT + 1) + o] = act ? acc : 0.f;
  }
  __syncthreads();
  if (tid < kT) {
    float s = 0.f, q = 0.f;
#pragma unroll 8
    for (int r = 0; r < 64; ++r) {
      float v = buf[r * (kT + 1) + tid];
      s += v;
      q = fmaf(v, v, q);
    }
    atomicAdd(stats + tid, s);
    atomicAdd(stats + kT + tid, q);
  }
}

// ------------- final graphnorm + relu (in place, 64-thr blocks) -------------
__global__ __launch_bounds__(64) void final_norm(
    const float* __restrict__ stats, const float* __restrict__ w,
    const float* __restrict__ b, const float* __restrict__ ms,
    float* __restrict__ out) {
  __shared__ float meanl[kT], rstdl[kT], wl2[kT], bl2[kT];
  const int tid = threadIdx.x;
  if (tid < kT) {
    float m = stats[tid] * (1.f / kN);
    float q = stats[kT + tid] * (1.f / kN);
    float msv = ms[tid];
    float var = q - m * m * msv * (2.f - msv);
    meanl[tid] = msv * m;
    rstdl[tid] = rsqrtf(var + kEps);
    wl2[tid] = w[tid];
    bl2[tid] = b[tid];
  }
  __syncthreads();
  const int node = blockIdx.x * 64 + tid;
  if (node >= kN) return;
  float* op = out + (size_t)node * kT;
#pragma unroll
  for (int o4 = 0; o4 < kT / 4; ++o4) {
    float4 v = *reinterpret_cast<const float4*>(op + o4 * 4);
    float r[4] = {v.x, v.y, v.z, v.w};
#pragma unroll
    for (int j = 0; j < 4; ++j) {
      int o = o4 * 4 + j;
      r[j] = fmaxf((r[j] - meanl[o]) * rstdl[o] * wl2[o] + bl2[o], 0.f);
    }
    *reinterpret_cast<float4*>(op + o4 * 4) =
        make_float4(r[0], r[1], r[2], r[3]);
  }
}

}  // namespace

extern "C" void kernel_launch(void* const* d_in, const int* in_sizes, int n_in,
                              void* d_out, int out_size, void* d_ws,
                              size_t ws_size, hipStream_t stream) {
  const float* x     = (const float*)d_in[0];
  const float* eattr = (const float*)d_in[1];
  const int*   eidx  = (const int*)d_in[2];
  const float* initW = (const float*)d_in[3];
  const float* initb = (const float*)d_in[4];
  const float* emW   = (const float*)d_in[5];
  const float* emb   = (const float*)d_in[6];
  const float* rW    = (const float*)d_in[7];
  const float* rb    = (const float*)d_in[8];
  const float* gnw   = (const float*)d_in[9];
  const float* gnb   = (const float*)d_in[10];
  const float* gnms  = (const float*)d_in[11];
  const float* tW    = (const float*)d_in[12];
  const float* tb    = (const float*)d_in[13];
  const float* fW    = (const float*)d_in[14];
  const float* fb    = (const float*)d_in[15];
  const float* fgw   = (const float*)d_in[16];
  const float* fgb   = (const float*)d_in[17];
  const float* fgms  = (const float*)d_in[18];
  float* out = (float*)d_out;

  // workspace layout (stats adjacent to cnt -> single memset for both)
  float* h     = (float*)d_ws;                       // kN*kH f32
  float* conv  = h + (size_t)kN * kH;                // kN*kH f32
  float* msg   = conv + (size_t)kN * kH;             // kE*kH f32
  unsigned short* wbf = (unsigned short*)(msg + (size_t)kE * kH);  // 196 KB
  float* stats = (float*)(wbf + (size_t)kL * 64 * 64 * 8);  // 512 f32
  int* cnt    = (int*)(stats + 512);                 // kN
  int* off    = cnt + kN;                            // kN
  int* rank   = off + kN;                            // kE

  const int node64  = (kN + 63) / 64;                // 313
  const int node256 = (kN + 255) / 256;              // 79
  const int edgeBlocks = kE / 64;                    // 1250 (4 waves x 16 edges)

  // single memset covers stats (512 f32) + cnt (kN ints), contiguous
  hipMemsetAsync(stats, 0, (512 + kN) * sizeof(float), stream);
  pack_w<<<kL * 64 * 64 / 256, 256, 0, stream>>>(emW, wbf);
  init_proj<<<node64, 64, 0, stream>>>(x, initW, initb, h);
  hist_dst<<<(kE + 255) / 256, 256, 0, stream>>>(eidx, cnt, rank);
  scan_nodes<<<1, 1024, 0, stream>>>(cnt, off);

  for (int l = 0; l < kL; ++l) {
    float* st = stats + l * 128;
    edge_msg_mfma<<<edgeBlocks, 256, 0, stream>>>(
        eattr, eidx, off, rank, h, wbf + (size_t)l * 64 * 64 * 8,
        emb + (size_t)l * kH * kH, msg);
    agg_root_stats<<<node256, 256, 0, stream>>>(
        msg, off, cnt, h, rW + (size_t)l * kH * kH, rb + l * kH, conv, st);
    norm_trans<<<node64, 64, 0, stream>>>(
        conv, st, gnw + l * kH, gnb + l * kH, gnms + l * kH,
        tW + (size_t)l * 2 * kH * kH, tb + l * kH, h);
  }
  final_lin<<<node64, 64, 0, stream>>>(h, fW, fb, out, stats + 3 * 128);
  final_norm<<<node64, 64, 0, stream>>>(stats + 3 * 128, fgw, fgb, fgms, out);
}